// Round 1
// baseline (1863.230 us; speedup 1.0000x reference)
//
#include <hip/hip_runtime.h>

#define N_NODES   1000000
#define N_EDGES   32000000
#define NUM_GRAPHS 1024

// Stage 1: agg[dst[e]] += x[src[e]] over all edges.
// edge_index is [2, N_EDGES] int32: row 0 = src, row 1 = dst.
// x (4 MB) and agg (4 MB) are L2/LLC-resident; edge reads are the HBM stream.
// Vectorize edge reads as int4 (4 edges per thread, 16B/lane loads).
__global__ void scatter_edges_kernel(const int4* __restrict__ src4,
                                     const int4* __restrict__ dst4,
                                     const float* __restrict__ x,
                                     float* __restrict__ agg) {
    int t = blockIdx.x * blockDim.x + threadIdx.x;
    if (t < N_EDGES / 4) {
        int4 s = src4[t];
        int4 d = dst4[t];
        float xs0 = x[s.x];
        float xs1 = x[s.y];
        float xs2 = x[s.z];
        float xs3 = x[s.w];
        atomicAdd(&agg[d.x], xs0);
        atomicAdd(&agg[d.y], xs1);
        atomicAdd(&agg[d.z], xs2);
        atomicAdd(&agg[d.w], xs3);
    }
}

// Stage 2: h = relu(agg); segment-sum h and counts into per-graph bins.
// batch is sorted, so almost every wave sees a single graph id:
// wave shuffle-reduce + 1 atomic per wave. Boundary waves fall back per-lane.
__global__ void pool_nodes_kernel(const float* __restrict__ agg,
                                  const int* __restrict__ batch,
                                  float* __restrict__ sums,
                                  float* __restrict__ counts) {
    int i = blockIdx.x * blockDim.x + threadIdx.x;
    float h = 0.0f;
    int g = -1;
    if (i < N_NODES) {
        h = fmaxf(agg[i], 0.0f);
        g = batch[i];
    }
    int g0 = __shfl(g, 0);            // wave-wide (64 lanes)
    if (__all(g == g0)) {
        // uniform wave: butterfly-free down-reduce
        #pragma unroll
        for (int off = 32; off > 0; off >>= 1)
            h += __shfl_down(h, off);
        if ((threadIdx.x & 63) == 0 && g0 >= 0) {
            atomicAdd(&sums[g0], h);
            atomicAdd(&counts[g0], 64.0f);
        }
    } else {
        if (g >= 0) {
            atomicAdd(&sums[g], h);
            atomicAdd(&counts[g], 1.0f);
        }
    }
}

// Stage 3: out[g] = (sums[g] / max(counts[g],1)) * W + b
__global__ void finalize_kernel(const float* __restrict__ sums,
                                const float* __restrict__ counts,
                                const float* __restrict__ W,
                                const float* __restrict__ b,
                                float* __restrict__ out) {
    int g = blockIdx.x * blockDim.x + threadIdx.x;
    if (g < NUM_GRAPHS) {
        float pooled = sums[g] / fmaxf(counts[g], 1.0f);
        out[g] = pooled * W[0] + b[0];
    }
}

extern "C" void kernel_launch(void* const* d_in, const int* in_sizes, int n_in,
                              void* d_out, int out_size, void* d_ws, size_t ws_size,
                              hipStream_t stream) {
    const float* x     = (const float*)d_in[0];
    const float* W     = (const float*)d_in[1];
    const float* b     = (const float*)d_in[2];
    const int*   edge  = (const int*)d_in[3];   // [2, N_EDGES] int32
    const int*   batch = (const int*)d_in[4];   // [N_NODES] int32, sorted
    float* out = (float*)d_out;

    // Workspace layout: agg[N_NODES] | sums[NUM_GRAPHS] | counts[NUM_GRAPHS]
    float* agg    = (float*)d_ws;
    float* sums   = agg + N_NODES;
    float* counts = sums + NUM_GRAPHS;

    // Zero-init (d_ws is poisoned 0xAA before every timed launch)
    hipMemsetAsync(d_ws, 0, (size_t)(N_NODES + 2 * NUM_GRAPHS) * sizeof(float), stream);

    const int* src = edge;             // row 0
    const int* dst = edge + N_EDGES;   // row 1 (offset 128 MB, 16B-aligned)

    {
        int nthreads = N_EDGES / 4;
        int block = 256;
        int grid = (nthreads + block - 1) / block;
        scatter_edges_kernel<<<grid, block, 0, stream>>>(
            (const int4*)src, (const int4*)dst, x, agg);
    }
    {
        int block = 256;
        int grid = (N_NODES + block - 1) / block;
        pool_nodes_kernel<<<grid, block, 0, stream>>>(agg, batch, sums, counts);
    }
    {
        int block = 256;
        int grid = (NUM_GRAPHS + block - 1) / block;
        finalize_kernel<<<grid, block, 0, stream>>>(sums, counts, W, b, out);
    }
}